// Round 3
// baseline (310.831 us; speedup 1.0000x reference)
//
#include <hip/hip_runtime.h>
#include <math.h>

typedef unsigned short UST;
typedef __attribute__((ext_vector_type(8))) short bf16x8;
typedef __attribute__((ext_vector_type(4))) float f32x4;

#define BB 4
#define LL 1024
#define IND 256
#define DD 512
#define HH 8
#define FFD 2048
#define NT (BB*LL)

__device__ __forceinline__ float bf2f(UST u){ return __uint_as_float(((unsigned)u)<<16); }
__device__ __forceinline__ UST f2bf(float f){
  unsigned u = __float_as_uint(f);
  u += 0x7FFFu + ((u>>16)&1u);
  return (UST)(u>>16);
}
__device__ __forceinline__ float ldF(const void* p, long i, int isf32){
  return isf32 ? ((const float*)p)[i] : bf2f(((const UST*)p)[i]);
}
__device__ __forceinline__ bool ldMask(const void* p, long i, int fm){
  if (fm==0) return ((const int*)p)[i] != 0;
  if (fm==1) return ((const unsigned char*)p)[i] != 0;
  if (fm==2) return ((const UST*)p)[i] != 0;
  return ((const float*)p)[i] != 0.f;
}
__device__ __forceinline__ f32x4 mfma16(bf16x8 a, bf16x8 b, f32x4 c){
  return __builtin_amdgcn_mfma_f32_16x16x32_bf16(a, b, c, 0, 0, 0);
}
__device__ __forceinline__ void gld16(const void* g, void* l){
  __builtin_amdgcn_global_load_lds((const __attribute__((address_space(1))) unsigned int*)g,
                                   (__attribute__((address_space(3))) unsigned int*)l, 16, 0, 0);
}

// ---------------- dtype detection (one wave) ----------------
__global__ void detect_k(int* flags, const UST* xh, const unsigned int* mw){
  int lane = threadIdx.x & 63;
  int e0 = (xh[lane] >> 7) & 0xFF;
  int e1 = (xh[64+lane] >> 7) & 0xFF;
  int f32 = __any((e0 >= 140) || (e1 >= 140)) ? 1 : 0;
  unsigned v = mw[lane];
  int w01   = __all(v <= 1u) ? 1 : 0;
  unsigned lo = v & 0xFFFFu, hi = v >> 16;
  int half  = __all((lo==0u||lo==0x3F80u) && (hi==0u||hi==0x3F80u)) ? 1 : 0;
  int wordF = __all(v==0u || v==0x3F800000u) ? 1 : 0;
  int byteB = __all((v & 0xFEFEFEFEu) == 0u) ? 1 : 0;
  if (lane == 0){
    flags[0] = f32;
    flags[1] = w01 ? 0 : (half ? (wordF ? 3 : 2) : (byteB ? 1 : 0));
  }
}

// ---------------- convert inputs to bf16 ws copies ----------------
struct CvtArgs { const void* src[11]; UST* dst[11]; int n[11]; };
__global__ __launch_bounds__(256) void cvt_k(const int* flags, CvtArgs a){
  int ti = blockIdx.y;
  int n = a.n[ti];
  long i8 = ((long)blockIdx.x*256 + threadIdx.x)*8;
  if (i8 >= n) return;
  const void* s = a.src[ti]; UST* d = a.dst[ti];
  if (flags[0]){
    const float4* sf = (const float4*)s;
    float4 a0 = sf[i8>>2], a1 = sf[(i8>>2)+1];
    UST o[8] = { f2bf(a0.x),f2bf(a0.y),f2bf(a0.z),f2bf(a0.w),
                 f2bf(a1.x),f2bf(a1.y),f2bf(a1.z),f2bf(a1.w) };
    *(int4*)(d+i8) = *(const int4*)o;
  } else {
    ((int4*)d)[i8>>3] = ((const int4*)s)[i8>>3];
  }
}

// ---------------- bias precompute: [B,L,L] bf16 ----------------
__global__ __launch_bounds__(256) void bias_k(const int* flags, const void* mask,
                                              const void* adj, const void* lsp, UST* biasOut){
  int fF = flags[0], fM = flags[1];
  int row = blockIdx.x;
  int i = row & (LL-1);
  long base = (long)row * LL;
  int t = threadIdx.x;
  bool mv[4]; int my = 1;
  #pragma unroll
  for (int k = 0; k < 4; ++k){
    mv[k] = ldMask(mask, base + t + k*256, fM);
    my &= mv[k] ? 1 : 0;
  }
  int wa = __all(my);
  __shared__ int sAll[4];
  int w = t >> 6;
  if ((t & 63) == 0) sAll[w] = wa;
  __syncthreads();
  int rowAll = sAll[0] & sAll[1] & sAll[2] & sAll[3];
  float es = expf(ldF(lsp, 0, fF));
  #pragma unroll
  for (int k = 0; k < 4; ++k){
    int j = t + k*256;
    float a = ldF(adj, base + j, fF);
    a = fminf(fmaxf(a, 0.f), 1.f);
    bool eff = mv[k] && !((rowAll != 0) && (j == i));
    float bz = (eff ? -10000.f : 0.f) + es * a;
    biasOut[base + j] = f2bf(bz);
  }
}

// ---------------- m97-style MFMA GEMM ----------------
template<int NI, int ACT, int RES, int OUTMODE>
__global__ __launch_bounds__(256) void gemm2_k(const int* flags,
    const UST* __restrict__ A, const UST* __restrict__ Bw, const UST* __restrict__ bias,
    const float* __restrict__ resid, void* Cout, int M, int N, int K){
  constexpr int TN = 32*NI;
  __shared__ UST sA[128*32];
  __shared__ UST sB[TN*32];
  int t = threadIdx.x, w = t>>6, lane = t&63, l15 = lane&15, qd = lane>>4;
  int m0 = blockIdx.x*128, n0 = blockIdx.y*TN;
  int wm = (w&1)*64, wn = (w>>1)*(NI*16);
  f32x4 acc[4][NI];
  #pragma unroll
  for (int mi=0; mi<4; ++mi)
    #pragma unroll
    for (int ni=0; ni<NI; ++ni){ acc[mi][ni][0]=0;acc[mi][ni][1]=0;acc[mi][ni][2]=0;acc[mi][ni][3]=0; }
  int arow = t>>2, acol = (t&3)*8;
  const UST* aSrc = A + (long)(m0+arow)*K + acol;
  const UST* bSrc = Bw + (long)(n0+arow)*K + acol;
  char* ldsA0 = (char*)sA + (w*64)*16;
  char* ldsA1 = (char*)sA + (256 + w*64)*16;
  char* ldsB0 = (char*)sB + (w*64)*16;
  char* ldsB1 = (char*)sB + (256 + w*64)*16;
  for (int k0 = 0; k0 < K; k0 += 32){
    __syncthreads();
    gld16(aSrc + k0, ldsA0);
    gld16(aSrc + 64*K + k0, ldsA1);
    gld16(bSrc + k0, ldsB0);
    if (NI == 4) gld16(bSrc + 64*K + k0, ldsB1);
    __syncthreads();
    bf16x8 afr[4], bfr[NI];
    #pragma unroll
    for (int mi=0; mi<4; ++mi) afr[mi] = *(const bf16x8*)&sA[(wm + mi*16 + l15)*32 + qd*8];
    #pragma unroll
    for (int ni=0; ni<NI; ++ni) bfr[ni] = *(const bf16x8*)&sB[(wn + ni*16 + l15)*32 + qd*8];
    #pragma unroll
    for (int mi=0; mi<4; ++mi)
      #pragma unroll
      for (int ni=0; ni<NI; ++ni)
        acc[mi][ni] = mfma16(afr[mi], bfr[ni], acc[mi][ni]);
  }
  int outF32 = (OUTMODE==1) || (OUTMODE==2 && flags[0]);
  #pragma unroll
  for (int mi=0; mi<4; ++mi){
    #pragma unroll
    for (int ni=0; ni<NI; ++ni){
      int gc = n0 + wn + ni*16 + l15;
      float bv = bf2f(bias[gc]);
      #pragma unroll
      for (int r=0; r<4; ++r){
        int grow = m0 + wm + mi*16 + qd*4 + r;
        float c = acc[mi][ni][r] + bv;
        if (ACT) c = 0.5f*c*(1.f+erff(c*0.70710678118654752f));
        long oi = (long)grow*N + gc;
        if (RES) c += resid[oi];
        if (outF32) ((float*)Cout)[oi] = c;
        else ((UST*)Cout)[oi] = f2bf(c);
      }
    }
  }
}

// ---------------- LayerNorm row kernel: fp32 in -> bf16 out ----------------
__global__ __launch_bounds__(256) void ln_k(const int* flags, const float* xin,
    const void* gp, const void* bp, UST* xout){
  int fF = flags[0];
  int row = blockIdx.x, t = threadIdx.x;
  const float* xr = xin + (long)row * DD;
  float v0 = xr[t], v1 = xr[t+256];
  float s = v0+v1, q = v0*v0 + v1*v1;
  #pragma unroll
  for (int off=1; off<64; off<<=1){ s += __shfl_xor(s,off,64); q += __shfl_xor(q,off,64); }
  __shared__ float rs[4], rq[4];
  int w = t>>6;
  if ((t&63)==0){ rs[w]=s; rq[w]=q; }
  __syncthreads();
  float S = rs[0]+rs[1]+rs[2]+rs[3];
  float Q = rq[0]+rq[1]+rq[2]+rq[3];
  float mean = S * (1.f/DD);
  float var  = fmaxf(Q * (1.f/DD) - mean*mean, 0.f);
  float ri = rsqrtf(var + 1e-5f);
  float g0 = ldF(gp, t, fF), b0 = ldF(bp, t, fF);
  float g1 = ldF(gp, t+256, fF), b1 = ldF(bp, t+256, fF);
  xout[(long)row*DD + t]     = f2bf((v0-mean)*ri*g0 + b0);
  xout[(long)row*DD + t+256] = f2bf((v1-mean)*ri*g1 + b1);
}

// ---------------- V transpose: qkv -> vT[b,h,d,token] ----------------
__global__ __launch_bounds__(256) void repack_v(const UST* __restrict__ qkv, UST* __restrict__ vT){
  int id = blockIdx.x;              // 512 = 32 bh * 16 qt
  int bh = id & 31, qt = id >> 5;
  int b = bh >> 3, h = bh & 7;
  int t = threadIdx.x, w = t >> 6, lane = t & 63;
  int token = qt*64 + lane;
  const UST* src = qkv + ((long)(b*LL + token))*1536 + 1024 + h*64;
  #pragma unroll
  for (int c = 0; c < 2; ++c){
    int ch = w*2 + c;
    union { int4 v; UST u[8]; } uu;
    uu.v = *(const int4*)(src + ch*8);
    #pragma unroll
    for (int i = 0; i < 8; ++i)
      vT[((long)(bh*64 + ch*8 + i))*LL + token] = uu.u[i];  // 128B coalesced per instr
  }
}

// ---------------- flash attention, barrier-free ----------------
// grid: 512 linear blocks; id = qt*32 + h*4 + b  =>  XCD(id%8) = b+4*(h&1):
// all 16 q-tiles of one (b,h) share an XCD -> K/V fetched ~once from HBM.
__global__ __launch_bounds__(256) void attn_k(const UST* __restrict__ qkv,
    const UST* __restrict__ vT, const UST* __restrict__ bias, UST* __restrict__ ctx){
  int id = blockIdx.x;
  int b = id & 3, h = (id>>2) & 7, qt = id >> 5;
  int bh = b*HH + h;
  int q0 = qt*64;
  int t = threadIdx.x, w = t>>6, lane = t&63, l15 = lane&15, qd = lane>>4;
  __shared__ UST sP[4][16*80];
  UST* myP = &sP[w][0];
  const UST* qrow = qkv + ((long)(b*LL + q0 + w*16 + l15))*1536 + h*64;
  bf16x8 qf0 = *(const bf16x8*)(qrow + qd*8);
  bf16x8 qf1 = *(const bf16x8*)(qrow + 32 + qd*8);
  const UST* bptr[4];
  #pragma unroll
  for (int r=0;r<4;++r)
    bptr[r] = bias + ((long)b<<20) + (long)(q0 + w*16 + qd*4 + r)*LL + l15;
  const UST* kBase = qkv + (long)b*LL*1536 + 512 + h*64;
  const UST* vBase = vT + (long)bh*64*LL;
  f32x4 o[4]; float mr_[4], lr_[4];
  #pragma unroll
  for (int i=0;i<4;i++){ o[i][0]=0;o[i][1]=0;o[i][2]=0;o[i][3]=0; mr_[i]=-1e30f; lr_[i]=0.f; }
  const float LOG2E = 1.44269504f;
  for (int kt = 0; kt < 16; ++kt){
    int k0 = kt*64;
    f32x4 s4[4];
    #pragma unroll
    for (int i=0;i<4;i++){ s4[i][0]=0;s4[i][1]=0;s4[i][2]=0;s4[i][3]=0; }
    #pragma unroll
    for (int ni=0; ni<4; ++ni){
      const UST* kp = kBase + (long)(k0 + ni*16 + l15)*1536 + qd*8;
      bf16x8 kf0 = *(const bf16x8*)kp;
      bf16x8 kf1 = *(const bf16x8*)(kp + 32);
      s4[ni] = mfma16(qf0, kf0, s4[ni]);
      s4[ni] = mfma16(qf1, kf1, s4[ni]);
    }
    float sv[4][4];
    #pragma unroll
    for (int ni=0; ni<4; ++ni)
      #pragma unroll
      for (int r=0; r<4; ++r)
        sv[ni][r] = fmaf(s4[ni][r], 0.125f, bf2f(bptr[r][k0 + ni*16]));
    float alpha[4];
    #pragma unroll
    for (int r=0; r<4; ++r){
      float mcur = fmaxf(fmaxf(sv[0][r],sv[1][r]), fmaxf(sv[2][r],sv[3][r]));
      #pragma unroll
      for (int off=1; off<16; off<<=1) mcur = fmaxf(mcur, __shfl_xor(mcur,off,64));
      float mn = fmaxf(mr_[r], mcur);
      alpha[r] = exp2f((mr_[r]-mn)*LOG2E);
      mr_[r] = mn;
      float mn2 = mn*LOG2E;
      float psum = 0.f;
      #pragma unroll
      for (int ni=0; ni<4; ++ni){
        float p = exp2f(fmaf(sv[ni][r], LOG2E, -mn2));
        sv[ni][r] = p; psum += p;
      }
      #pragma unroll
      for (int off=1; off<16; off<<=1) psum += __shfl_xor(psum,off,64);
      lr_[r] = lr_[r]*alpha[r] + psum;
    }
    #pragma unroll
    for (int dn=0; dn<4; ++dn)
      #pragma unroll
      for (int r=0; r<4; ++r) o[dn][r] *= alpha[r];
    #pragma unroll
    for (int ni=0; ni<4; ++ni)
      #pragma unroll
      for (int r=0; r<4; ++r) myP[(qd*4+r)*80 + ni*16 + l15] = f2bf(sv[ni][r]);
    bf16x8 pf0 = *(const bf16x8*)&myP[l15*80 + qd*8];
    bf16x8 pf1 = *(const bf16x8*)&myP[l15*80 + 32 + qd*8];
    #pragma unroll
    for (int dn=0; dn<4; ++dn){
      const UST* vp = vBase + (long)(dn*16 + l15)*LL + k0 + qd*8;
      bf16x8 vf0 = *(const bf16x8*)vp;
      bf16x8 vf1 = *(const bf16x8*)(vp + 32);
      o[dn] = mfma16(pf0, vf0, o[dn]);
      o[dn] = mfma16(pf1, vf1, o[dn]);
    }
  }
  #pragma unroll
  for (int dn=0; dn<4; ++dn){
    #pragma unroll
    for (int r=0; r<4; ++r){
      long oi = ((long)(b*LL + q0 + w*16 + qd*4 + r))*DD + h*64 + dn*16 + l15;
      ctx[oi] = f2bf(o[dn][r] * (1.f/lr_[r]));
    }
  }
}

extern "C" void kernel_launch(void* const* d_in, const int* in_sizes, int n_in,
                              void* d_out, int out_size, void* d_ws, size_t ws_size,
                              hipStream_t stream){
  char* ws = (char*)d_ws;
  size_t o = 0;
  auto alloc = [&](size_t b){ size_t r = o; o += (b + 255) & ~(size_t)255; return r; };
  int*   flags = (int*)(ws + alloc(256));
  size_t biasOff = alloc(8UL<<20);          // biasC 8MB
  size_t qkvOff  = alloc(12UL<<20);         // qkv 12MB
  UST* biasC = (UST*)(ws + biasOff);
  UST* qkv   = (UST*)(ws + qkvOff);
  UST* hb    = (UST*)(ws + biasOff);        // 16MB, aliases biasC+qkv (dead by ffn1)
  UST* vT    = (UST*)(ws + alloc(4UL<<20)); // V^T [bh,d,token] 4MB
  UST* xbf   = (UST*)(ws + alloc(2UL<<20));
  UST* wfuse = (UST*)(ws + alloc(131072*2));
  UST* bfuse = (UST*)(ws + alloc(1024));
  UST* ipw   = (UST*)(ws + alloc(786432*2));
  UST* ipb   = (UST*)(ws + alloc(3072*2));
  UST* outw  = (UST*)(ws + alloc(262144*2));
  UST* outb  = (UST*)(ws + alloc(1024));
  UST* w1    = (UST*)(ws + alloc(1048576*2));
  UST* b1    = (UST*)(ws + alloc(4096*2));
  UST* w2    = (UST*)(ws + alloc(1048576*2));
  UST* b2    = (UST*)(ws + alloc(1024));
  float* xf  = (float*)(ws + alloc((size_t)NT*DD*4));
  UST* xn    = (UST*)(ws + alloc((size_t)NT*DD*2));
  UST* ctx   = (UST*)(ws + alloc((size_t)NT*DD*2));
  float* x2  = (float*)(ws + alloc((size_t)NT*DD*4));

  detect_k<<<1, 64, 0, stream>>>(flags, (const UST*)d_in[0], (const unsigned int*)d_in[1]);

  CvtArgs ca;
  const int srcIdx[11] = {0,3,4,5,6,7,8,13,14,15,16};
  UST* dsts[11] = {xbf,wfuse,bfuse,ipw,ipb,outw,outb,w1,b1,w2,b2};
  const int ns[11] = {NT*IND, DD*IND, DD, 3*DD*DD, 3*DD, DD*DD, DD, FFD*DD, FFD, DD*FFD, DD};
  for (int i=0;i<11;i++){ ca.src[i]=d_in[srcIdx[i]]; ca.dst[i]=dsts[i]; ca.n[i]=ns[i]; }
  cvt_k<<<dim3(512,11), 256, 0, stream>>>(flags, ca);

  bias_k<<<BB*LL, 256, 0, stream>>>(flags, d_in[1], d_in[2], d_in[17], biasC);

  gemm2_k<2,0,0,1><<<dim3(32,8), 256, 0, stream>>>(flags, xbf, wfuse, bfuse, nullptr, xf, NT, DD, IND);
  ln_k<<<NT, 256, 0, stream>>>(flags, xf, d_in[9], d_in[10], xn);
  gemm2_k<4,0,0,0><<<dim3(32,12), 256, 0, stream>>>(flags, xn, ipw, ipb, nullptr, qkv, NT, 3*DD, DD);
  repack_v<<<512, 256, 0, stream>>>(qkv, vT);
  attn_k<<<512, 256, 0, stream>>>(qkv, vT, biasC, ctx);
  gemm2_k<2,0,1,1><<<dim3(32,8), 256, 0, stream>>>(flags, ctx, outw, outb, xf, x2, NT, DD, DD);
  ln_k<<<NT, 256, 0, stream>>>(flags, x2, d_in[11], d_in[12], xn);
  gemm2_k<4,1,0,0><<<dim3(32,16), 256, 0, stream>>>(flags, xn, w1, b1, nullptr, hb, NT, FFD, DD);
  gemm2_k<2,0,1,2><<<dim3(32,8), 256, 0, stream>>>(flags, hb, w2, b2, x2, d_out, NT, DD, FFD);
}

// Round 4
// 284.738 us; speedup vs baseline: 1.0916x; 1.0916x over previous
//
#include <hip/hip_runtime.h>
#include <math.h>

typedef unsigned short UST;
typedef __attribute__((ext_vector_type(8))) short bf16x8;
typedef __attribute__((ext_vector_type(4))) float f32x4;

#define BB 4
#define LL 1024
#define IND 256
#define DD 512
#define HH 8
#define FFD 2048
#define NT (BB*LL)

__device__ __forceinline__ float bf2f(UST u){ return __uint_as_float(((unsigned)u)<<16); }
__device__ __forceinline__ UST f2bf(float f){
  unsigned u = __float_as_uint(f);
  u += 0x7FFFu + ((u>>16)&1u);
  return (UST)(u>>16);
}
__device__ __forceinline__ float ldF(const void* p, long i, int isf32){
  return isf32 ? ((const float*)p)[i] : bf2f(((const UST*)p)[i]);
}
__device__ __forceinline__ bool ldMask(const void* p, long i, int fm){
  if (fm==0) return ((const int*)p)[i] != 0;
  if (fm==1) return ((const unsigned char*)p)[i] != 0;
  if (fm==2) return ((const UST*)p)[i] != 0;
  return ((const float*)p)[i] != 0.f;
}
__device__ __forceinline__ f32x4 mfma16(bf16x8 a, bf16x8 b, f32x4 c){
  return __builtin_amdgcn_mfma_f32_16x16x32_bf16(a, b, c, 0, 0, 0);
}
__device__ __forceinline__ void gld16(const void* g, void* l){
  __builtin_amdgcn_global_load_lds((const __attribute__((address_space(1))) unsigned int*)g,
                                   (__attribute__((address_space(3))) unsigned int*)l, 16, 0, 0);
}

// ---------------- dtype detection (one wave) ----------------
__global__ void detect_k(int* flags, const UST* xh, const unsigned int* mw){
  int lane = threadIdx.x & 63;
  int e0 = (xh[lane] >> 7) & 0xFF;
  int e1 = (xh[64+lane] >> 7) & 0xFF;
  int f32 = __any((e0 >= 140) || (e1 >= 140)) ? 1 : 0;
  unsigned v = mw[lane];
  int w01   = __all(v <= 1u) ? 1 : 0;
  unsigned lo = v & 0xFFFFu, hi = v >> 16;
  int half  = __all((lo==0u||lo==0x3F80u) && (hi==0u||hi==0x3F80u)) ? 1 : 0;
  int wordF = __all(v==0u || v==0x3F800000u) ? 1 : 0;
  int byteB = __all((v & 0xFEFEFEFEu) == 0u) ? 1 : 0;
  if (lane == 0){
    flags[0] = f32;
    flags[1] = w01 ? 0 : (half ? (wordF ? 3 : 2) : (byteB ? 1 : 0));
  }
}

// ---------------- convert inputs to bf16 ws copies ----------------
struct CvtArgs { const void* src[11]; UST* dst[11]; int n[11]; };
__global__ __launch_bounds__(256) void cvt_k(const int* flags, CvtArgs a){
  int ti = blockIdx.y;
  int n = a.n[ti];
  long i8 = ((long)blockIdx.x*256 + threadIdx.x)*8;
  if (i8 >= n) return;
  const void* s = a.src[ti]; UST* d = a.dst[ti];
  if (flags[0]){
    const float4* sf = (const float4*)s;
    float4 a0 = sf[i8>>2], a1 = sf[(i8>>2)+1];
    UST o[8] = { f2bf(a0.x),f2bf(a0.y),f2bf(a0.z),f2bf(a0.w),
                 f2bf(a1.x),f2bf(a1.y),f2bf(a1.z),f2bf(a1.w) };
    *(int4*)(d+i8) = *(const int4*)o;
  } else {
    ((int4*)d)[i8>>3] = ((const int4*)s)[i8>>3];
  }
}

// ---------------- bias precompute: [B,L,L] bf16, vectorized x4 ----------------
__global__ __launch_bounds__(256) void bias_k(const int* flags, const void* mask,
                                              const void* adj, const void* lsp, UST* biasOut){
  int fF = flags[0], fM = flags[1];
  int row = blockIdx.x;
  int i = row & (LL-1);
  long base = (long)row * LL;
  int t = threadIdx.x;
  int j0 = t*4;
  bool mv[4];
  if (fM == 0){
    int4 m4 = *(const int4*)((const int*)mask + base + j0);
    mv[0]=m4.x!=0; mv[1]=m4.y!=0; mv[2]=m4.z!=0; mv[3]=m4.w!=0;
  } else {
    #pragma unroll
    for (int k=0;k<4;++k) mv[k] = ldMask(mask, base + j0 + k, fM);
  }
  float a4[4];
  if (fF){
    float4 av = *(const float4*)((const float*)adj + base + j0);
    a4[0]=av.x; a4[1]=av.y; a4[2]=av.z; a4[3]=av.w;
  } else {
    const UST* ap = (const UST*)adj + base + j0;
    #pragma unroll
    for (int k=0;k<4;++k) a4[k] = bf2f(ap[k]);
  }
  int my = (mv[0]&&mv[1]&&mv[2]&&mv[3]) ? 1 : 0;
  int wa = __all(my);
  __shared__ int sAll[4];
  int w = t >> 6;
  if ((t & 63) == 0) sAll[w] = wa;
  __syncthreads();
  int rowAll = sAll[0] & sAll[1] & sAll[2] & sAll[3];
  float es = expf(ldF(lsp, 0, fF));
  UST o4[4];
  #pragma unroll
  for (int k = 0; k < 4; ++k){
    int j = j0 + k;
    float a = fminf(fmaxf(a4[k], 0.f), 1.f);
    bool eff = mv[k] && !((rowAll != 0) && (j == i));
    o4[k] = f2bf((eff ? -10000.f : 0.f) + es * a);
  }
  *(int2*)(biasOut + base + j0) = *(const int2*)o4;
}

// ---------------- m97-style MFMA GEMM ----------------
template<int NI, int ACT, int RES, int OUTMODE>
__global__ __launch_bounds__(256) void gemm2_k(const int* flags,
    const UST* __restrict__ A, const UST* __restrict__ Bw, const UST* __restrict__ bias,
    const float* __restrict__ resid, void* Cout, int M, int N, int K){
  constexpr int TN = 32*NI;
  __shared__ UST sA[128*32];
  __shared__ UST sB[TN*32];
  int t = threadIdx.x, w = t>>6, lane = t&63, l15 = lane&15, qd = lane>>4;
  int m0 = blockIdx.x*128, n0 = blockIdx.y*TN;
  int wm = (w&1)*64, wn = (w>>1)*(NI*16);
  f32x4 acc[4][NI];
  #pragma unroll
  for (int mi=0; mi<4; ++mi)
    #pragma unroll
    for (int ni=0; ni<NI; ++ni){ acc[mi][ni][0]=0;acc[mi][ni][1]=0;acc[mi][ni][2]=0;acc[mi][ni][3]=0; }
  int arow = t>>2, acol = (t&3)*8;
  const UST* aSrc = A + (long)(m0+arow)*K + acol;
  const UST* bSrc = Bw + (long)(n0+arow)*K + acol;
  char* ldsA0 = (char*)sA + (w*64)*16;
  char* ldsA1 = (char*)sA + (256 + w*64)*16;
  char* ldsB0 = (char*)sB + (w*64)*16;
  char* ldsB1 = (char*)sB + (256 + w*64)*16;
  for (int k0 = 0; k0 < K; k0 += 32){
    __syncthreads();
    gld16(aSrc + k0, ldsA0);
    gld16(aSrc + 64*K + k0, ldsA1);
    gld16(bSrc + k0, ldsB0);
    if (NI == 4) gld16(bSrc + 64*K + k0, ldsB1);
    __syncthreads();
    bf16x8 afr[4], bfr[NI];
    #pragma unroll
    for (int mi=0; mi<4; ++mi) afr[mi] = *(const bf16x8*)&sA[(wm + mi*16 + l15)*32 + qd*8];
    #pragma unroll
    for (int ni=0; ni<NI; ++ni) bfr[ni] = *(const bf16x8*)&sB[(wn + ni*16 + l15)*32 + qd*8];
    #pragma unroll
    for (int mi=0; mi<4; ++mi)
      #pragma unroll
      for (int ni=0; ni<NI; ++ni)
        acc[mi][ni] = mfma16(afr[mi], bfr[ni], acc[mi][ni]);
  }
  int outF32 = (OUTMODE==1) || (OUTMODE==2 && flags[0]);
  #pragma unroll
  for (int mi=0; mi<4; ++mi){
    #pragma unroll
    for (int ni=0; ni<NI; ++ni){
      int gc = n0 + wn + ni*16 + l15;
      float bv = bf2f(bias[gc]);
      #pragma unroll
      for (int r=0; r<4; ++r){
        int grow = m0 + wm + mi*16 + qd*4 + r;
        float c = acc[mi][ni][r] + bv;
        if (ACT) c = 0.5f*c*(1.f+erff(c*0.70710678118654752f));
        long oi = (long)grow*N + gc;
        if (RES) c += resid[oi];
        if (outF32) ((float*)Cout)[oi] = c;
        else ((UST*)Cout)[oi] = f2bf(c);
      }
    }
  }
}

// ---------------- LayerNorm row kernel: fp32 in -> bf16 out ----------------
__global__ __launch_bounds__(256) void ln_k(const int* flags, const float* xin,
    const void* gp, const void* bp, UST* xout){
  int fF = flags[0];
  int row = blockIdx.x, t = threadIdx.x;
  const float* xr = xin + (long)row * DD;
  float v0 = xr[t], v1 = xr[t+256];
  float s = v0+v1, q = v0*v0 + v1*v1;
  #pragma unroll
  for (int off=1; off<64; off<<=1){ s += __shfl_xor(s,off,64); q += __shfl_xor(q,off,64); }
  __shared__ float rs[4], rq[4];
  int w = t>>6;
  if ((t&63)==0){ rs[w]=s; rq[w]=q; }
  __syncthreads();
  float S = rs[0]+rs[1]+rs[2]+rs[3];
  float Q = rq[0]+rq[1]+rq[2]+rq[3];
  float mean = S * (1.f/DD);
  float var  = fmaxf(Q * (1.f/DD) - mean*mean, 0.f);
  float ri = rsqrtf(var + 1e-5f);
  float g0 = ldF(gp, t, fF), b0 = ldF(bp, t, fF);
  float g1 = ldF(gp, t+256, fF), b1 = ldF(bp, t+256, fF);
  xout[(long)row*DD + t]     = f2bf((v0-mean)*ri*g0 + b0);
  xout[(long)row*DD + t+256] = f2bf((v1-mean)*ri*g1 + b1);
}

// ---------------- V transpose: qkv -> vT[b,h,d,token] ----------------
__global__ __launch_bounds__(256) void repack_v(const UST* __restrict__ qkv, UST* __restrict__ vT){
  int id = blockIdx.x;              // 512 = 32 bh * 16 qt
  int bh = id & 31, qt = id >> 5;
  int b = bh >> 3, h = bh & 7;
  int t = threadIdx.x, w = t >> 6, lane = t & 63;
  int token = qt*64 + lane;
  const UST* src = qkv + ((long)(b*LL + token))*1536 + 1024 + h*64;
  #pragma unroll
  for (int c = 0; c < 2; ++c){
    int ch = w*2 + c;
    union { int4 v; UST u[8]; } uu;
    uu.v = *(const int4*)(src + ch*8);
    #pragma unroll
    for (int i = 0; i < 8; ++i)
      vT[((long)(bh*64 + ch*8 + i))*LL + token] = uu.u[i];
  }
}

// ---------------- flash attention: coalesced LDS staging via global_load_lds ----
// grid 512; id = qt*32 + h*4 + b  => all 16 q-tiles of one (b,h) on one XCD.
__global__ __launch_bounds__(256) void attn_k(const UST* __restrict__ qkv,
    const UST* __restrict__ vT, const UST* __restrict__ bias, UST* __restrict__ ctx){
  int id = blockIdx.x;
  int b = id & 3, h = (id>>2) & 7, qt = id >> 5;
  int bh = b*HH + h;
  int q0 = qt*64;
  int t = threadIdx.x, w = t>>6, lane = t&63, l15 = lane&15, qd = lane>>4;
  // staged tiles: rows x 32 features (64B rows -> proven gemm2 LDS/bank pattern)
  __shared__ UST sK0[64*32], sK1[64*32];
  __shared__ UST sV0[64*32], sV1[64*32];
  __shared__ UST sB0[64*32], sB1[64*32];
  __shared__ UST sP[4][16*72];
  UST* myP = &sP[w][0];

  const UST* qrow = qkv + ((long)(b*LL + q0 + w*16 + l15))*1536 + h*64;
  bf16x8 qf0 = *(const bf16x8*)(qrow + qd*8);
  bf16x8 qf1 = *(const bf16x8*)(qrow + 32 + qd*8);

  int rowS = t>>2, colS = (t&3)*8;            // staging: row, col(UST)
  const UST* kS = qkv + (long)(b*LL + rowS)*1536 + 512 + h*64 + colS;
  const UST* vS = vT + (long)(bh*64 + rowS)*LL + colS;
  const UST* bS = bias + ((long)b<<20) + (long)(q0 + rowS)*LL + colS;
  char* dK0 = (char*)sK0 + w*1024; char* dK1 = (char*)sK1 + w*1024;
  char* dV0 = (char*)sV0 + w*1024; char* dV1 = (char*)sV1 + w*1024;
  char* dB0 = (char*)sB0 + w*1024; char* dB1 = (char*)sB1 + w*1024;

  f32x4 o[4]; float mr_[4], lr_[4];
  #pragma unroll
  for (int i=0;i<4;i++){ o[i][0]=0;o[i][1]=0;o[i][2]=0;o[i][3]=0; mr_[i]=-1e30f; lr_[i]=0.f; }
  const float LOG2E = 1.44269504f;

  for (int kt = 0; kt < 16; ++kt){
    int k0 = kt*64;
    __syncthreads();
    gld16(kS + (long)k0*1536,      dK0);
    gld16(kS + (long)k0*1536 + 32, dK1);
    gld16(vS + k0,                 dV0);
    gld16(vS + k0 + 32,            dV1);
    gld16(bS + k0,                 dB0);
    gld16(bS + k0 + 32,            dB1);
    __syncthreads();

    f32x4 s4[4];
    #pragma unroll
    for (int i=0;i<4;i++){ s4[i][0]=0;s4[i][1]=0;s4[i][2]=0;s4[i][3]=0; }
    #pragma unroll
    for (int ni=0; ni<4; ++ni){
      bf16x8 kf0 = *(const bf16x8*)&sK0[(ni*16+l15)*32 + qd*8];
      bf16x8 kf1 = *(const bf16x8*)&sK1[(ni*16+l15)*32 + qd*8];
      s4[ni] = mfma16(qf0, kf0, s4[ni]);
      s4[ni] = mfma16(qf1, kf1, s4[ni]);
    }
    float sv[4][4];
    #pragma unroll
    for (int ni=0; ni<4; ++ni){
      const UST* sBc = (ni < 2) ? sB0 : sB1;
      int nc = (ni & 1)*16 + l15;
      #pragma unroll
      for (int r=0; r<4; ++r){
        float bzv = bf2f(sBc[(w*16 + qd*4 + r)*32 + nc]);
        sv[ni][r] = fmaf(s4[ni][r], 0.125f, bzv);
      }
    }
    float alpha[4];
    #pragma unroll
    for (int r=0; r<4; ++r){
      float mcur = fmaxf(fmaxf(sv[0][r],sv[1][r]), fmaxf(sv[2][r],sv[3][r]));
      #pragma unroll
      for (int off=1; off<16; off<<=1) mcur = fmaxf(mcur, __shfl_xor(mcur,off,64));
      float mn = fmaxf(mr_[r], mcur);
      alpha[r] = exp2f((mr_[r]-mn)*LOG2E);
      mr_[r] = mn;
      float mn2 = mn*LOG2E;
      float psum = 0.f;
      #pragma unroll
      for (int ni=0; ni<4; ++ni){
        float p = exp2f(fmaf(sv[ni][r], LOG2E, -mn2));
        sv[ni][r] = p; psum += p;
      }
      #pragma unroll
      for (int off=1; off<16; off<<=1) psum += __shfl_xor(psum,off,64);
      lr_[r] = lr_[r]*alpha[r] + psum;
    }
    #pragma unroll
    for (int dn=0; dn<4; ++dn)
      #pragma unroll
      for (int r=0; r<4; ++r) o[dn][r] *= alpha[r];
    #pragma unroll
    for (int ni=0; ni<4; ++ni)
      #pragma unroll
      for (int r=0; r<4; ++r) myP[(qd*4+r)*72 + ni*16 + l15] = f2bf(sv[ni][r]);
    bf16x8 pf0 = *(const bf16x8*)&myP[l15*72 + qd*8];
    bf16x8 pf1 = *(const bf16x8*)&myP[l15*72 + 32 + qd*8];
    #pragma unroll
    for (int dn=0; dn<4; ++dn){
      bf16x8 vf0 = *(const bf16x8*)&sV0[(dn*16+l15)*32 + qd*8];
      bf16x8 vf1 = *(const bf16x8*)&sV1[(dn*16+l15)*32 + qd*8];
      o[dn] = mfma16(pf0, vf0, o[dn]);
      o[dn] = mfma16(pf1, vf1, o[dn]);
    }
  }
  #pragma unroll
  for (int dn=0; dn<4; ++dn){
    #pragma unroll
    for (int r=0; r<4; ++r){
      long oi = ((long)(b*LL + q0 + w*16 + qd*4 + r))*DD + h*64 + dn*16 + l15;
      ctx[oi] = f2bf(o[dn][r] * (1.f/lr_[r]));
    }
  }
}

extern "C" void kernel_launch(void* const* d_in, const int* in_sizes, int n_in,
                              void* d_out, int out_size, void* d_ws, size_t ws_size,
                              hipStream_t stream){
  char* ws = (char*)d_ws;
  size_t o = 0;
  auto alloc = [&](size_t b){ size_t r = o; o += (b + 255) & ~(size_t)255; return r; };
  int*   flags = (int*)(ws + alloc(256));
  size_t biasOff = alloc(8UL<<20);
  size_t qkvOff  = alloc(12UL<<20);
  UST* biasC = (UST*)(ws + biasOff);
  UST* qkv   = (UST*)(ws + qkvOff);
  UST* hb    = (UST*)(ws + biasOff);        // aliases biasC+qkv (dead by ffn1)
  UST* vT    = (UST*)(ws + alloc(4UL<<20));
  UST* xbf   = (UST*)(ws + alloc(2UL<<20));
  UST* wfuse = (UST*)(ws + alloc(131072*2));
  UST* bfuse = (UST*)(ws + alloc(1024));
  UST* ipw   = (UST*)(ws + alloc(786432*2));
  UST* ipb   = (UST*)(ws + alloc(3072*2));
  UST* outw  = (UST*)(ws + alloc(262144*2));
  UST* outb  = (UST*)(ws + alloc(1024));
  UST* w1    = (UST*)(ws + alloc(1048576*2));
  UST* b1    = (UST*)(ws + alloc(4096*2));
  UST* w2    = (UST*)(ws + alloc(1048576*2));
  UST* b2    = (UST*)(ws + alloc(1024));
  float* xf  = (float*)(ws + alloc((size_t)NT*DD*4));
  UST* xn    = (UST*)(ws + alloc((size_t)NT*DD*2));
  UST* ctx   = (UST*)(ws + alloc((size_t)NT*DD*2));
  float* x2  = (float*)(ws + alloc((size_t)NT*DD*4));

  detect_k<<<1, 64, 0, stream>>>(flags, (const UST*)d_in[0], (const unsigned int*)d_in[1]);

  CvtArgs ca;
  const int srcIdx[11] = {0,3,4,5,6,7,8,13,14,15,16};
  UST* dsts[11] = {xbf,wfuse,bfuse,ipw,ipb,outw,outb,w1,b1,w2,b2};
  const int ns[11] = {NT*IND, DD*IND, DD, 3*DD*DD, 3*DD, DD*DD, DD, FFD*DD, FFD, DD*FFD, DD};
  for (int i=0;i<11;i++){ ca.src[i]=d_in[srcIdx[i]]; ca.dst[i]=dsts[i]; ca.n[i]=ns[i]; }
  cvt_k<<<dim3(512,11), 256, 0, stream>>>(flags, ca);

  bias_k<<<BB*LL, 256, 0, stream>>>(flags, d_in[1], d_in[2], d_in[17], biasC);

  gemm2_k<2,0,0,1><<<dim3(32,8), 256, 0, stream>>>(flags, xbf, wfuse, bfuse, nullptr, xf, NT, DD, IND);
  ln_k<<<NT, 256, 0, stream>>>(flags, xf, d_in[9], d_in[10], xn);
  gemm2_k<4,0,0,0><<<dim3(32,12), 256, 0, stream>>>(flags, xn, ipw, ipb, nullptr, qkv, NT, 3*DD, DD);
  repack_v<<<512, 256, 0, stream>>>(qkv, vT);
  attn_k<<<512, 256, 0, stream>>>(qkv, vT, biasC, ctx);
  gemm2_k<2,0,1,1><<<dim3(32,8), 256, 0, stream>>>(flags, ctx, outw, outb, xf, x2, NT, DD, DD);
  ln_k<<<NT, 256, 0, stream>>>(flags, x2, d_in[11], d_in[12], xn);
  gemm2_k<4,1,0,0><<<dim3(32,16), 256, 0, stream>>>(flags, xn, w1, b1, nullptr, hb, NT, FFD, DD);
  gemm2_k<2,0,1,2><<<dim3(32,8), 256, 0, stream>>>(flags, hb, w2, b2, x2, d_out, NT, DD, FFD);
}

// Round 5
// 274.708 us; speedup vs baseline: 1.1315x; 1.0365x over previous
//
#include <hip/hip_runtime.h>
#include <math.h>

typedef unsigned short UST;
typedef __attribute__((ext_vector_type(8))) short bf16x8;
typedef __attribute__((ext_vector_type(4))) float f32x4;

#define BB 4
#define LL 1024
#define IND 256
#define DD 512
#define HH 8
#define FFD 2048
#define NT (BB*LL)

__device__ __forceinline__ float bf2f(UST u){ return __uint_as_float(((unsigned)u)<<16); }
__device__ __forceinline__ UST f2bf(float f){
  unsigned u = __float_as_uint(f);
  u += 0x7FFFu + ((u>>16)&1u);
  return (UST)(u>>16);
}
__device__ __forceinline__ float ldF(const void* p, long i, int isf32){
  return isf32 ? ((const float*)p)[i] : bf2f(((const UST*)p)[i]);
}
__device__ __forceinline__ bool ldMask(const void* p, long i, int fm){
  if (fm==0) return ((const int*)p)[i] != 0;
  if (fm==1) return ((const unsigned char*)p)[i] != 0;
  if (fm==2) return ((const UST*)p)[i] != 0;
  return ((const float*)p)[i] != 0.f;
}
__device__ __forceinline__ f32x4 mfma16(bf16x8 a, bf16x8 b, f32x4 c){
  return __builtin_amdgcn_mfma_f32_16x16x32_bf16(a, b, c, 0, 0, 0);
}
__device__ __forceinline__ void gld16(const void* g, void* l){
  __builtin_amdgcn_global_load_lds((const __attribute__((address_space(1))) unsigned int*)g,
                                   (__attribute__((address_space(3))) unsigned int*)l, 16, 0, 0);
}

// ---------------- dtype detection (one wave) ----------------
__global__ void detect_k(int* flags, const UST* xh, const unsigned int* mw){
  int lane = threadIdx.x & 63;
  int e0 = (xh[lane] >> 7) & 0xFF;
  int e1 = (xh[64+lane] >> 7) & 0xFF;
  int f32 = __any((e0 >= 140) || (e1 >= 140)) ? 1 : 0;
  unsigned v = mw[lane];
  int w01   = __all(v <= 1u) ? 1 : 0;
  unsigned lo = v & 0xFFFFu, hi = v >> 16;
  int half  = __all((lo==0u||lo==0x3F80u) && (hi==0u||hi==0x3F80u)) ? 1 : 0;
  int wordF = __all(v==0u || v==0x3F800000u) ? 1 : 0;
  int byteB = __all((v & 0xFEFEFEFEu) == 0u) ? 1 : 0;
  if (lane == 0){
    flags[0] = f32;
    flags[1] = w01 ? 0 : (half ? (wordF ? 3 : 2) : (byteB ? 1 : 0));
  }
}

// ---------------- convert inputs to bf16 ws copies ----------------
struct CvtArgs { const void* src[11]; UST* dst[11]; int n[11]; };
__global__ __launch_bounds__(256) void cvt_k(const int* flags, CvtArgs a){
  int ti = blockIdx.y;
  int n = a.n[ti];
  long i8 = ((long)blockIdx.x*256 + threadIdx.x)*8;
  if (i8 >= n) return;
  const void* s = a.src[ti]; UST* d = a.dst[ti];
  if (flags[0]){
    const float4* sf = (const float4*)s;
    float4 a0 = sf[i8>>2], a1 = sf[(i8>>2)+1];
    UST o[8] = { f2bf(a0.x),f2bf(a0.y),f2bf(a0.z),f2bf(a0.w),
                 f2bf(a1.x),f2bf(a1.y),f2bf(a1.z),f2bf(a1.w) };
    *(int4*)(d+i8) = *(const int4*)o;
  } else {
    ((int4*)d)[i8>>3] = ((const int4*)s)[i8>>3];
  }
}

// ---------------- bias precompute: [B,L,L] bf16, vectorized x4 ----------------
__global__ __launch_bounds__(256) void bias_k(const int* flags, const void* mask,
                                              const void* adj, const void* lsp, UST* biasOut){
  int fF = flags[0], fM = flags[1];
  int row = blockIdx.x;
  int i = row & (LL-1);
  long base = (long)row * LL;
  int t = threadIdx.x;
  int j0 = t*4;
  bool mv[4];
  if (fM == 0){
    int4 m4 = *(const int4*)((const int*)mask + base + j0);
    mv[0]=m4.x!=0; mv[1]=m4.y!=0; mv[2]=m4.z!=0; mv[3]=m4.w!=0;
  } else {
    #pragma unroll
    for (int k=0;k<4;++k) mv[k] = ldMask(mask, base + j0 + k, fM);
  }
  float a4[4];
  if (fF){
    float4 av = *(const float4*)((const float*)adj + base + j0);
    a4[0]=av.x; a4[1]=av.y; a4[2]=av.z; a4[3]=av.w;
  } else {
    const UST* ap = (const UST*)adj + base + j0;
    #pragma unroll
    for (int k=0;k<4;++k) a4[k] = bf2f(ap[k]);
  }
  int my = (mv[0]&&mv[1]&&mv[2]&&mv[3]) ? 1 : 0;
  int wa = __all(my);
  __shared__ int sAll[4];
  int w = t >> 6;
  if ((t & 63) == 0) sAll[w] = wa;
  __syncthreads();
  int rowAll = sAll[0] & sAll[1] & sAll[2] & sAll[3];
  float es = expf(ldF(lsp, 0, fF));
  UST o4[4];
  #pragma unroll
  for (int k = 0; k < 4; ++k){
    int j = j0 + k;
    float a = fminf(fmaxf(a4[k], 0.f), 1.f);
    bool eff = mv[k] && !((rowAll != 0) && (j == i));
    o4[k] = f2bf((eff ? -10000.f : 0.f) + es * a);
  }
  *(int2*)(biasOut + base + j0) = *(const int2*)o4;
}

// ---------------- MFMA GEMM with double-buffered async prefetch ----------------
// iter: barrier -> issue loads->buf_nxt -> compute buf_cur. vmcnt(0) at the barrier
// drains loads that flew during the PREVIOUS iter's compute (true overlap).
template<int NI, int ACT, int RES, int OUTMODE>
__global__ __launch_bounds__(256) void gemm2_k(const int* flags,
    const UST* __restrict__ A, const UST* __restrict__ Bw, const UST* __restrict__ bias,
    const float* __restrict__ resid, void* Cout, int M, int N, int K){
  constexpr int TN = 32*NI;
  __shared__ UST sA[2][128*32];
  __shared__ UST sB[2][TN*32];
  int t = threadIdx.x, w = t>>6, lane = t&63, l15 = lane&15, qd = lane>>4;
  int m0 = blockIdx.x*128, n0 = blockIdx.y*TN;
  int wm = (w&1)*64, wn = (w>>1)*(NI*16);
  f32x4 acc[4][NI];
  #pragma unroll
  for (int mi=0; mi<4; ++mi)
    #pragma unroll
    for (int ni=0; ni<NI; ++ni){ acc[mi][ni][0]=0;acc[mi][ni][1]=0;acc[mi][ni][2]=0;acc[mi][ni][3]=0; }
  int arow = t>>2, acol = (t&3)*8;
  const UST* aSrc = A + (long)(m0+arow)*K + acol;
  const UST* bSrc = Bw + (long)(n0+arow)*K + acol;
  // prolog: stage first tile into buf 0
  gld16(aSrc,        (char*)sA[0] + w*1024);
  gld16(aSrc + 64*K, (char*)sA[0] + 4096 + w*1024);
  gld16(bSrc,        (char*)sB[0] + w*1024);
  if (NI == 4) gld16(bSrc + 64*K, (char*)sB[0] + 4096 + w*1024);
  for (int k0 = 0; k0 < K; k0 += 32){
    int cur = (k0>>5)&1, nxt = cur^1;
    __syncthreads();
    if (k0 + 32 < K){
      gld16(aSrc + k0+32,        (char*)sA[nxt] + w*1024);
      gld16(aSrc + 64*K + k0+32, (char*)sA[nxt] + 4096 + w*1024);
      gld16(bSrc + k0+32,        (char*)sB[nxt] + w*1024);
      if (NI == 4) gld16(bSrc + 64*K + k0+32, (char*)sB[nxt] + 4096 + w*1024);
    }
    bf16x8 afr[4], bfr[NI];
    #pragma unroll
    for (int mi=0; mi<4; ++mi) afr[mi] = *(const bf16x8*)&sA[cur][(wm + mi*16 + l15)*32 + qd*8];
    #pragma unroll
    for (int ni=0; ni<NI; ++ni) bfr[ni] = *(const bf16x8*)&sB[cur][(wn + ni*16 + l15)*32 + qd*8];
    #pragma unroll
    for (int mi=0; mi<4; ++mi)
      #pragma unroll
      for (int ni=0; ni<NI; ++ni)
        acc[mi][ni] = mfma16(afr[mi], bfr[ni], acc[mi][ni]);
  }
  int outF32 = (OUTMODE==1) || (OUTMODE==2 && flags[0]);
  #pragma unroll
  for (int mi=0; mi<4; ++mi){
    #pragma unroll
    for (int ni=0; ni<NI; ++ni){
      int gc = n0 + wn + ni*16 + l15;
      float bv = bf2f(bias[gc]);
      #pragma unroll
      for (int r=0; r<4; ++r){
        int grow = m0 + wm + mi*16 + qd*4 + r;
        float c = acc[mi][ni][r] + bv;
        if (ACT) c = 0.5f*c*(1.f+erff(c*0.70710678118654752f));
        long oi = (long)grow*N + gc;
        if (RES) c += resid[oi];
        if (outF32) ((float*)Cout)[oi] = c;
        else ((UST*)Cout)[oi] = f2bf(c);
      }
    }
  }
}

// ---------------- LayerNorm row kernel: fp32 in -> bf16 out ----------------
__global__ __launch_bounds__(256) void ln_k(const int* flags, const float* xin,
    const void* gp, const void* bp, UST* xout){
  int fF = flags[0];
  int row = blockIdx.x, t = threadIdx.x;
  const float* xr = xin + (long)row * DD;
  float v0 = xr[t], v1 = xr[t+256];
  float s = v0+v1, q = v0*v0 + v1*v1;
  #pragma unroll
  for (int off=1; off<64; off<<=1){ s += __shfl_xor(s,off,64); q += __shfl_xor(q,off,64); }
  __shared__ float rs[4], rq[4];
  int w = t>>6;
  if ((t&63)==0){ rs[w]=s; rq[w]=q; }
  __syncthreads();
  float S = rs[0]+rs[1]+rs[2]+rs[3];
  float Q = rq[0]+rq[1]+rq[2]+rq[3];
  float mean = S * (1.f/DD);
  float var  = fmaxf(Q * (1.f/DD) - mean*mean, 0.f);
  float ri = rsqrtf(var + 1e-5f);
  float g0 = ldF(gp, t, fF), b0 = ldF(bp, t, fF);
  float g1 = ldF(gp, t+256, fF), b1 = ldF(bp, t+256, fF);
  xout[(long)row*DD + t]     = f2bf((v0-mean)*ri*g0 + b0);
  xout[(long)row*DD + t+256] = f2bf((v1-mean)*ri*g1 + b1);
}

// ---------------- V transpose: qkv -> vT[b,h,d,token] ----------------
__global__ __launch_bounds__(256) void repack_v(const UST* __restrict__ qkv, UST* __restrict__ vT){
  int id = blockIdx.x;
  int bh = id & 31, qt = id >> 5;
  int b = bh >> 3, h = bh & 7;
  int t = threadIdx.x, w = t >> 6, lane = t & 63;
  int token = qt*64 + lane;
  const UST* src = qkv + ((long)(b*LL + token))*1536 + 1024 + h*64;
  #pragma unroll
  for (int c = 0; c < 2; ++c){
    int ch = w*2 + c;
    union { int4 v; UST u[8]; } uu;
    uu.v = *(const int4*)(src + ch*8);
    #pragma unroll
    for (int i = 0; i < 8; ++i)
      vT[((long)(bh*64 + ch*8 + i))*LL + token] = uu.u[i];
  }
}

// ---------------- flash attention: dbuf async staging, 1 barrier/iter ----------
__global__ __launch_bounds__(256) void attn_k(const UST* __restrict__ qkv,
    const UST* __restrict__ vT, const UST* __restrict__ bias, UST* __restrict__ ctx){
  int id = blockIdx.x;
  int b = id & 3, h = (id>>2) & 7, qt = id >> 5;
  int bh = b*HH + h;
  int q0 = qt*64;
  int t = threadIdx.x, w = t>>6, lane = t&63, l15 = lane&15, qd = lane>>4;
  __shared__ UST sK[2][2][64*32];   // [buf][chunk]
  __shared__ UST sV[2][2][64*32];
  __shared__ UST sB[2][2][64*32];
  __shared__ UST sP[4][16*72];
  UST* myP = &sP[w][0];

  const UST* qrow = qkv + ((long)(b*LL + q0 + w*16 + l15))*1536 + h*64;
  bf16x8 qf0 = *(const bf16x8*)(qrow + qd*8);
  bf16x8 qf1 = *(const bf16x8*)(qrow + 32 + qd*8);

  int rowS = t>>2, colS = (t&3)*8;
  const UST* kS = qkv + (long)(b*LL + rowS)*1536 + 512 + h*64 + colS;
  const UST* vS = vT + (long)(bh*64 + rowS)*LL + colS;
  const UST* bS = bias + ((long)b<<20) + (long)(q0 + rowS)*LL + colS;

  f32x4 o[4]; float mr_[4], lr_[4];
  #pragma unroll
  for (int i=0;i<4;i++){ o[i][0]=0;o[i][1]=0;o[i][2]=0;o[i][3]=0; mr_[i]=-1e30f; lr_[i]=0.f; }
  const float LOG2E = 1.44269504f;

  // prolog: stage kt=0 into buf 0
  gld16(kS,      (char*)sK[0][0] + w*1024);
  gld16(kS + 32, (char*)sK[0][1] + w*1024);
  gld16(vS,      (char*)sV[0][0] + w*1024);
  gld16(vS + 32, (char*)sV[0][1] + w*1024);
  gld16(bS,      (char*)sB[0][0] + w*1024);
  gld16(bS + 32, (char*)sB[0][1] + w*1024);

  for (int kt = 0; kt < 16; ++kt){
    int cur = kt&1, nxt = cur^1;
    int k0 = kt*64;
    __syncthreads();
    if (kt < 15){
      int kn = k0 + 64;
      gld16(kS + (long)kn*1536,      (char*)sK[nxt][0] + w*1024);
      gld16(kS + (long)kn*1536 + 32, (char*)sK[nxt][1] + w*1024);
      gld16(vS + kn,                 (char*)sV[nxt][0] + w*1024);
      gld16(vS + kn + 32,            (char*)sV[nxt][1] + w*1024);
      gld16(bS + kn,                 (char*)sB[nxt][0] + w*1024);
      gld16(bS + kn + 32,            (char*)sB[nxt][1] + w*1024);
    }
    f32x4 s4[4];
    #pragma unroll
    for (int i=0;i<4;i++){ s4[i][0]=0;s4[i][1]=0;s4[i][2]=0;s4[i][3]=0; }
    #pragma unroll
    for (int ni=0; ni<4; ++ni){
      bf16x8 kf0 = *(const bf16x8*)&sK[cur][0][(ni*16+l15)*32 + qd*8];
      bf16x8 kf1 = *(const bf16x8*)&sK[cur][1][(ni*16+l15)*32 + qd*8];
      s4[ni] = mfma16(qf0, kf0, s4[ni]);
      s4[ni] = mfma16(qf1, kf1, s4[ni]);
    }
    float sv[4][4];
    #pragma unroll
    for (int ni=0; ni<4; ++ni){
      const UST* sBc = sB[cur][ni>>1];
      int nc = (ni & 1)*16 + l15;
      #pragma unroll
      for (int r=0; r<4; ++r){
        float bzv = bf2f(sBc[(w*16 + qd*4 + r)*32 + nc]);
        sv[ni][r] = fmaf(s4[ni][r], 0.125f, bzv);
      }
    }
    float alpha[4];
    #pragma unroll
    for (int r=0; r<4; ++r){
      float mcur = fmaxf(fmaxf(sv[0][r],sv[1][r]), fmaxf(sv[2][r],sv[3][r]));
      #pragma unroll
      for (int off=1; off<16; off<<=1) mcur = fmaxf(mcur, __shfl_xor(mcur,off,64));
      float mn = fmaxf(mr_[r], mcur);
      alpha[r] = exp2f((mr_[r]-mn)*LOG2E);
      mr_[r] = mn;
      float mn2 = mn*LOG2E;
      float psum = 0.f;
      #pragma unroll
      for (int ni=0; ni<4; ++ni){
        float p = exp2f(fmaf(sv[ni][r], LOG2E, -mn2));
        sv[ni][r] = p; psum += p;
      }
      #pragma unroll
      for (int off=1; off<16; off<<=1) psum += __shfl_xor(psum,off,64);
      lr_[r] = lr_[r]*alpha[r] + psum;
    }
    #pragma unroll
    for (int dn=0; dn<4; ++dn)
      #pragma unroll
      for (int r=0; r<4; ++r) o[dn][r] *= alpha[r];
    #pragma unroll
    for (int ni=0; ni<4; ++ni)
      #pragma unroll
      for (int r=0; r<4; ++r) myP[(qd*4+r)*72 + ni*16 + l15] = f2bf(sv[ni][r]);
    bf16x8 pf0 = *(const bf16x8*)&myP[l15*72 + qd*8];
    bf16x8 pf1 = *(const bf16x8*)&myP[l15*72 + 32 + qd*8];
    #pragma unroll
    for (int dn=0; dn<4; ++dn){
      bf16x8 vf0 = *(const bf16x8*)&sV[cur][0][(dn*16+l15)*32 + qd*8];
      bf16x8 vf1 = *(const bf16x8*)&sV[cur][1][(dn*16+l15)*32 + qd*8];
      o[dn] = mfma16(pf0, vf0, o[dn]);
      o[dn] = mfma16(pf1, vf1, o[dn]);
    }
  }
  #pragma unroll
  for (int dn=0; dn<4; ++dn){
    #pragma unroll
    for (int r=0; r<4; ++r){
      long oi = ((long)(b*LL + q0 + w*16 + qd*4 + r))*DD + h*64 + dn*16 + l15;
      ctx[oi] = f2bf(o[dn][r] * (1.f/lr_[r]));
    }
  }
}

extern "C" void kernel_launch(void* const* d_in, const int* in_sizes, int n_in,
                              void* d_out, int out_size, void* d_ws, size_t ws_size,
                              hipStream_t stream){
  char* ws = (char*)d_ws;
  size_t o = 0;
  auto alloc = [&](size_t b){ size_t r = o; o += (b + 255) & ~(size_t)255; return r; };
  int*   flags = (int*)(ws + alloc(256));
  size_t biasOff = alloc(8UL<<20);
  size_t qkvOff  = alloc(12UL<<20);
  UST* biasC = (UST*)(ws + biasOff);
  UST* qkv   = (UST*)(ws + qkvOff);
  UST* hb    = (UST*)(ws + biasOff);        // aliases biasC+qkv (dead by ffn1)
  UST* vT    = (UST*)(ws + alloc(4UL<<20));
  UST* xbf   = (UST*)(ws + alloc(2UL<<20));
  UST* wfuse = (UST*)(ws + alloc(131072*2));
  UST* bfuse = (UST*)(ws + alloc(1024));
  UST* ipw   = (UST*)(ws + alloc(786432*2));
  UST* ipb   = (UST*)(ws + alloc(3072*2));
  UST* outw  = (UST*)(ws + alloc(262144*2));
  UST* outb  = (UST*)(ws + alloc(1024));
  UST* w1    = (UST*)(ws + alloc(1048576*2));
  UST* b1    = (UST*)(ws + alloc(4096*2));
  UST* w2    = (UST*)(ws + alloc(1048576*2));
  UST* b2    = (UST*)(ws + alloc(1024));
  float* xf  = (float*)(ws + alloc((size_t)NT*DD*4));
  UST* xn    = (UST*)(ws + alloc((size_t)NT*DD*2));
  UST* ctx   = (UST*)(ws + alloc((size_t)NT*DD*2));
  float* x2  = (float*)(ws + alloc((size_t)NT*DD*4));

  detect_k<<<1, 64, 0, stream>>>(flags, (const UST*)d_in[0], (const unsigned int*)d_in[1]);

  CvtArgs ca;
  const int srcIdx[11] = {0,3,4,5,6,7,8,13,14,15,16};
  UST* dsts[11] = {xbf,wfuse,bfuse,ipw,ipb,outw,outb,w1,b1,w2,b2};
  const int ns[11] = {NT*IND, DD*IND, DD, 3*DD*DD, 3*DD, DD*DD, DD, FFD*DD, FFD, DD*FFD, DD};
  for (int i=0;i<11;i++){ ca.src[i]=d_in[srcIdx[i]]; ca.dst[i]=dsts[i]; ca.n[i]=ns[i]; }
  cvt_k<<<dim3(512,11), 256, 0, stream>>>(flags, ca);

  bias_k<<<BB*LL, 256, 0, stream>>>(flags, d_in[1], d_in[2], d_in[17], biasC);

  gemm2_k<2,0,0,1><<<dim3(32,8), 256, 0, stream>>>(flags, xbf, wfuse, bfuse, nullptr, xf, NT, DD, IND);
  ln_k<<<NT, 256, 0, stream>>>(flags, xf, d_in[9], d_in[10], xn);
  gemm2_k<4,0,0,0><<<dim3(32,12), 256, 0, stream>>>(flags, xn, ipw, ipb, nullptr, qkv, NT, 3*DD, DD);
  repack_v<<<512, 256, 0, stream>>>(qkv, vT);
  attn_k<<<512, 256, 0, stream>>>(qkv, vT, biasC, ctx);
  gemm2_k<2,0,1,1><<<dim3(32,8), 256, 0, stream>>>(flags, ctx, outw, outb, xf, x2, NT, DD, DD);
  ln_k<<<NT, 256, 0, stream>>>(flags, x2, d_in[11], d_in[12], xn);
  gemm2_k<4,1,0,0><<<dim3(32,16), 256, 0, stream>>>(flags, xn, w1, b1, nullptr, hb, NT, FFD, DD);
  gemm2_k<2,0,1,2><<<dim3(32,8), 256, 0, stream>>>(flags, hb, w2, b2, x2, d_out, NT, DD, FFD);
}

// Round 6
// 262.919 us; speedup vs baseline: 1.1822x; 1.0448x over previous
//
#include <hip/hip_runtime.h>
#include <math.h>

typedef unsigned short UST;
typedef __attribute__((ext_vector_type(8))) short bf16x8;
typedef __attribute__((ext_vector_type(4))) float f32x4;

#define BB 4
#define LL 1024
#define IND 256
#define DD 512
#define HH 8
#define FFD 2048
#define NT (BB*LL)

__device__ __forceinline__ float bf2f(UST u){ return __uint_as_float(((unsigned)u)<<16); }
__device__ __forceinline__ UST f2bf(float f){
  unsigned u = __float_as_uint(f);
  u += 0x7FFFu + ((u>>16)&1u);
  return (UST)(u>>16);
}
__device__ __forceinline__ float ldF(const void* p, long i, int isf32){
  return isf32 ? ((const float*)p)[i] : bf2f(((const UST*)p)[i]);
}
__device__ __forceinline__ bool ldMask(const void* p, long i, int fm){
  if (fm==0) return ((const int*)p)[i] != 0;
  if (fm==1) return ((const unsigned char*)p)[i] != 0;
  if (fm==2) return ((const UST*)p)[i] != 0;
  return ((const float*)p)[i] != 0.f;
}
__device__ __forceinline__ f32x4 mfma16(bf16x8 a, bf16x8 b, f32x4 c){
  return __builtin_amdgcn_mfma_f32_16x16x32_bf16(a, b, c, 0, 0, 0);
}
__device__ __forceinline__ void gld16(const void* g, void* l){
  __builtin_amdgcn_global_load_lds((const __attribute__((address_space(1))) unsigned int*)g,
                                   (__attribute__((address_space(3))) unsigned int*)l, 16, 0, 0);
}

// ---------------- dtype detection (one wave) ----------------
__global__ void detect_k(int* flags, const UST* xh, const unsigned int* mw){
  int lane = threadIdx.x & 63;
  int e0 = (xh[lane] >> 7) & 0xFF;
  int e1 = (xh[64+lane] >> 7) & 0xFF;
  int f32 = __any((e0 >= 140) || (e1 >= 140)) ? 1 : 0;
  unsigned v = mw[lane];
  int w01   = __all(v <= 1u) ? 1 : 0;
  unsigned lo = v & 0xFFFFu, hi = v >> 16;
  int half  = __all((lo==0u||lo==0x3F80u) && (hi==0u||hi==0x3F80u)) ? 1 : 0;
  int wordF = __all(v==0u || v==0x3F800000u) ? 1 : 0;
  int byteB = __all((v & 0xFEFEFEFEu) == 0u) ? 1 : 0;
  if (lane == 0){
    flags[0] = f32;
    flags[1] = w01 ? 0 : (half ? (wordF ? 3 : 2) : (byteB ? 1 : 0));
  }
}

// ---------------- convert inputs to bf16 ws copies ----------------
struct CvtArgs { const void* src[11]; UST* dst[11]; int n[11]; };
__global__ __launch_bounds__(256) void cvt_k(const int* flags, CvtArgs a){
  int ti = blockIdx.y;
  int n = a.n[ti];
  long i8 = ((long)blockIdx.x*256 + threadIdx.x)*8;
  if (i8 >= n) return;
  const void* s = a.src[ti]; UST* d = a.dst[ti];
  if (flags[0]){
    const float4* sf = (const float4*)s;
    float4 a0 = sf[i8>>2], a1 = sf[(i8>>2)+1];
    UST o[8] = { f2bf(a0.x),f2bf(a0.y),f2bf(a0.z),f2bf(a0.w),
                 f2bf(a1.x),f2bf(a1.y),f2bf(a1.z),f2bf(a1.w) };
    *(int4*)(d+i8) = *(const int4*)o;
  } else {
    ((int4*)d)[i8>>3] = ((const int4*)s)[i8>>3];
  }
}

// ---------------- bias precompute: [B,L,L] bf16, PRE-SCALED by log2(e) ----------------
__global__ __launch_bounds__(256) void bias_k(const int* flags, const void* mask,
                                              const void* adj, const void* lsp, UST* biasOut){
  int fF = flags[0], fM = flags[1];
  int row = blockIdx.x;
  int i = row & (LL-1);
  long base = (long)row * LL;
  int t = threadIdx.x;
  int j0 = t*4;
  bool mv[4];
  if (fM == 0){
    int4 m4 = *(const int4*)((const int*)mask + base + j0);
    mv[0]=m4.x!=0; mv[1]=m4.y!=0; mv[2]=m4.z!=0; mv[3]=m4.w!=0;
  } else {
    #pragma unroll
    for (int k=0;k<4;++k) mv[k] = ldMask(mask, base + j0 + k, fM);
  }
  float a4[4];
  if (fF){
    float4 av = *(const float4*)((const float*)adj + base + j0);
    a4[0]=av.x; a4[1]=av.y; a4[2]=av.z; a4[3]=av.w;
  } else {
    const UST* ap = (const UST*)adj + base + j0;
    #pragma unroll
    for (int k=0;k<4;++k) a4[k] = bf2f(ap[k]);
  }
  int my = (mv[0]&&mv[1]&&mv[2]&&mv[3]) ? 1 : 0;
  int wa = __all(my);
  __shared__ int sAll[4];
  int w = t >> 6;
  if ((t & 63) == 0) sAll[w] = wa;
  __syncthreads();
  int rowAll = sAll[0] & sAll[1] & sAll[2] & sAll[3];
  float es = expf(ldF(lsp, 0, fF));
  UST o4[4];
  #pragma unroll
  for (int k = 0; k < 4; ++k){
    int j = j0 + k;
    float a = fminf(fmaxf(a4[k], 0.f), 1.f);
    bool eff = mv[k] && !((rowAll != 0) && (j == i));
    o4[k] = f2bf(((eff ? -10000.f : 0.f) + es * a) * 1.44269504f);
  }
  *(int2*)(biasOut + base + j0) = *(const int2*)o4;
}

// ---------------- MFMA GEMM: BK=64, double-buffered async prefetch ----------------
// 32 MFMA per barrier (NI=4). iter: barrier -> prefetch nxt -> compute cur (2 k-substeps).
template<int NI, int ACT, int RES, int OUTMODE>
__global__ __launch_bounds__(256) void gemm2_k(const int* flags,
    const UST* __restrict__ A, const UST* __restrict__ Bw, const UST* __restrict__ bias,
    const float* __restrict__ resid, void* Cout, int M, int N, int K){
  constexpr int TN = 32*NI;
  __shared__ UST sA[2][128*64];
  __shared__ UST sB[2][TN*64];
  int t = threadIdx.x, w = t>>6, lane = t&63, l15 = lane&15, qd = lane>>4;
  int m0 = blockIdx.x*128, n0 = blockIdx.y*TN;
  int wm = (w&1)*64, wn = (w>>1)*(NI*16);
  f32x4 acc[4][NI];
  #pragma unroll
  for (int mi=0; mi<4; ++mi)
    #pragma unroll
    for (int ni=0; ni<NI; ++ni){ acc[mi][ni][0]=0;acc[mi][ni][1]=0;acc[mi][ni][2]=0;acc[mi][ni][3]=0; }
  // staging: 8-row x 64-col chunks; lane covers row lane>>3, cols (lane&7)*8
  int sRow = lane>>3, sCol = (lane&7)*8;
  const UST* aS = A + (long)(m0 + w*32 + sRow)*K + sCol;
  const UST* bS = Bw + (long)(n0 + w*(TN/4) + sRow)*K + sCol;
  #define STAGE(buf, k0) { \
    _Pragma("unroll") \
    for (int c=0;c<4;++c) gld16(aS + (long)c*8*K + (k0), (char*)&sA[buf][(w*32 + c*8)*64]); \
    _Pragma("unroll") \
    for (int c=0;c<NI;++c) gld16(bS + (long)c*8*K + (k0), (char*)&sB[buf][(w*(TN/4) + c*8)*64]); }
  STAGE(0, 0)
  for (int k0 = 0; k0 < K; k0 += 64){
    int cur = (k0>>6)&1, nxt = cur^1;
    __syncthreads();
    if (k0 + 64 < K) STAGE(nxt, k0+64)
    #pragma unroll
    for (int ks=0; ks<2; ++ks){
      bf16x8 afr[4], bfr[NI];
      #pragma unroll
      for (int mi=0; mi<4; ++mi) afr[mi] = *(const bf16x8*)&sA[cur][(wm + mi*16 + l15)*64 + ks*32 + qd*8];
      #pragma unroll
      for (int ni=0; ni<NI; ++ni) bfr[ni] = *(const bf16x8*)&sB[cur][(wn + ni*16 + l15)*64 + ks*32 + qd*8];
      #pragma unroll
      for (int mi=0; mi<4; ++mi)
        #pragma unroll
        for (int ni=0; ni<NI; ++ni)
          acc[mi][ni] = mfma16(afr[mi], bfr[ni], acc[mi][ni]);
    }
  }
  #undef STAGE
  int outF32 = (OUTMODE==1) || (OUTMODE==2 && flags[0]);
  #pragma unroll
  for (int mi=0; mi<4; ++mi){
    #pragma unroll
    for (int ni=0; ni<NI; ++ni){
      int gc = n0 + wn + ni*16 + l15;
      float bv = bf2f(bias[gc]);
      #pragma unroll
      for (int r=0; r<4; ++r){
        int grow = m0 + wm + mi*16 + qd*4 + r;
        float c = acc[mi][ni][r] + bv;
        if (ACT) c = 0.5f*c*(1.f+erff(c*0.70710678118654752f));
        long oi = (long)grow*N + gc;
        if (RES) c += resid[oi];
        if (outF32) ((float*)Cout)[oi] = c;
        else ((UST*)Cout)[oi] = f2bf(c);
      }
    }
  }
}

// ---------------- LayerNorm row kernel: fp32 in -> bf16 out ----------------
__global__ __launch_bounds__(256) void ln_k(const int* flags, const float* xin,
    const void* gp, const void* bp, UST* xout){
  int fF = flags[0];
  int row = blockIdx.x, t = threadIdx.x;
  const float* xr = xin + (long)row * DD;
  float v0 = xr[t], v1 = xr[t+256];
  float s = v0+v1, q = v0*v0 + v1*v1;
  #pragma unroll
  for (int off=1; off<64; off<<=1){ s += __shfl_xor(s,off,64); q += __shfl_xor(q,off,64); }
  __shared__ float rs[4], rq[4];
  int w = t>>6;
  if ((t&63)==0){ rs[w]=s; rq[w]=q; }
  __syncthreads();
  float S = rs[0]+rs[1]+rs[2]+rs[3];
  float Q = rq[0]+rq[1]+rq[2]+rq[3];
  float mean = S * (1.f/DD);
  float var  = fmaxf(Q * (1.f/DD) - mean*mean, 0.f);
  float ri = rsqrtf(var + 1e-5f);
  float g0 = ldF(gp, t, fF), b0 = ldF(bp, t, fF);
  float g1 = ldF(gp, t+256, fF), b1 = ldF(bp, t+256, fF);
  xout[(long)row*DD + t]     = f2bf((v0-mean)*ri*g0 + b0);
  xout[(long)row*DD + t+256] = f2bf((v1-mean)*ri*g1 + b1);
}

// ---------------- V transpose: qkv -> vT[b,h,d,token] ----------------
__global__ __launch_bounds__(256) void repack_v(const UST* __restrict__ qkv, UST* __restrict__ vT){
  int id = blockIdx.x;
  int bh = id & 31, qt = id >> 5;
  int b = bh >> 3, h = bh & 7;
  int t = threadIdx.x, w = t >> 6, lane = t & 63;
  int token = qt*64 + lane;
  const UST* src = qkv + ((long)(b*LL + token))*1536 + 1024 + h*64;
  #pragma unroll
  for (int c = 0; c < 2; ++c){
    int ch = w*2 + c;
    union { int4 v; UST u[8]; } uu;
    uu.v = *(const int4*)(src + ch*8);
    #pragma unroll
    for (int i = 0; i < 8; ++i)
      vT[((long)(bh*64 + ch*8 + i))*LL + token] = uu.u[i];
  }
}

// ---------------- flash attention: no-max softmax (scores bounded; masked
// entries are -1e4 -> exp underflows to 0; >=1 live entry per row guaranteed).
// l accumulated per-lane, reduced ONCE at the end. dbuf async staging.
__global__ __launch_bounds__(256) void attn_k(const UST* __restrict__ qkv,
    const UST* __restrict__ vT, const UST* __restrict__ bias, UST* __restrict__ ctx){
  int id = blockIdx.x;
  int b = id & 3, h = (id>>2) & 7, qt = id >> 5;
  int bh = b*HH + h;
  int q0 = qt*64;
  int t = threadIdx.x, w = t>>6, lane = t&63, l15 = lane&15, qd = lane>>4;
  __shared__ UST sK[2][2][64*32];
  __shared__ UST sV[2][2][64*32];
  __shared__ UST sB[2][2][64*32];
  __shared__ UST sP[4][16*72];
  UST* myP = &sP[w][0];

  const UST* qrow = qkv + ((long)(b*LL + q0 + w*16 + l15))*1536 + h*64;
  bf16x8 qf0 = *(const bf16x8*)(qrow + qd*8);
  bf16x8 qf1 = *(const bf16x8*)(qrow + 32 + qd*8);

  int rowS = t>>2, colS = (t&3)*8;
  const UST* kS = qkv + (long)(b*LL + rowS)*1536 + 512 + h*64 + colS;
  const UST* vS = vT + (long)(bh*64 + rowS)*LL + colS;
  const UST* bS = bias + ((long)b<<20) + (long)(q0 + rowS)*LL + colS;

  f32x4 o[4]; float lsum[4];
  #pragma unroll
  for (int i=0;i<4;i++){ o[i][0]=0;o[i][1]=0;o[i][2]=0;o[i][3]=0; lsum[i]=0.f; }
  const float C1 = 0.18033688f;   // 0.125 * log2(e); bias already pre-scaled by log2(e)

  gld16(kS,      (char*)sK[0][0] + w*1024);
  gld16(kS + 32, (char*)sK[0][1] + w*1024);
  gld16(vS,      (char*)sV[0][0] + w*1024);
  gld16(vS + 32, (char*)sV[0][1] + w*1024);
  gld16(bS,      (char*)sB[0][0] + w*1024);
  gld16(bS + 32, (char*)sB[0][1] + w*1024);

  for (int kt = 0; kt < 16; ++kt){
    int cur = kt&1, nxt = cur^1;
    int k0 = kt*64;
    __syncthreads();
    if (kt < 15){
      int kn = k0 + 64;
      gld16(kS + (long)kn*1536,      (char*)sK[nxt][0] + w*1024);
      gld16(kS + (long)kn*1536 + 32, (char*)sK[nxt][1] + w*1024);
      gld16(vS + kn,                 (char*)sV[nxt][0] + w*1024);
      gld16(vS + kn + 32,            (char*)sV[nxt][1] + w*1024);
      gld16(bS + kn,                 (char*)sB[nxt][0] + w*1024);
      gld16(bS + kn + 32,            (char*)sB[nxt][1] + w*1024);
    }
    f32x4 s4[4];
    #pragma unroll
    for (int i=0;i<4;i++){ s4[i][0]=0;s4[i][1]=0;s4[i][2]=0;s4[i][3]=0; }
    #pragma unroll
    for (int ni=0; ni<4; ++ni){
      bf16x8 kf0 = *(const bf16x8*)&sK[cur][0][(ni*16+l15)*32 + qd*8];
      bf16x8 kf1 = *(const bf16x8*)&sK[cur][1][(ni*16+l15)*32 + qd*8];
      s4[ni] = mfma16(qf0, kf0, s4[ni]);
      s4[ni] = mfma16(qf1, kf1, s4[ni]);
    }
    float p[4][4];
    #pragma unroll
    for (int ni=0; ni<4; ++ni){
      const UST* sBc = sB[cur][ni>>1];
      int nc = (ni & 1)*16 + l15;
      #pragma unroll
      for (int r=0; r<4; ++r){
        float bzv = bf2f(sBc[(w*16 + qd*4 + r)*32 + nc]);
        p[ni][r] = exp2f(fmaf(s4[ni][r], C1, bzv));
      }
    }
    #pragma unroll
    for (int r=0; r<4; ++r)
      lsum[r] += (p[0][r]+p[1][r]) + (p[2][r]+p[3][r]);
    #pragma unroll
    for (int ni=0; ni<4; ++ni)
      #pragma unroll
      for (int r=0; r<4; ++r) myP[(qd*4+r)*72 + ni*16 + l15] = f2bf(p[ni][r]);
    bf16x8 pf0 = *(const bf16x8*)&myP[l15*72 + qd*8];
    bf16x8 pf1 = *(const bf16x8*)&myP[l15*72 + 32 + qd*8];
    #pragma unroll
    for (int dn=0; dn<4; ++dn){
      bf16x8 vf0 = *(const bf16x8*)&sV[cur][0][(dn*16+l15)*32 + qd*8];
      bf16x8 vf1 = *(const bf16x8*)&sV[cur][1][(dn*16+l15)*32 + qd*8];
      o[dn] = mfma16(pf0, vf0, o[dn]);
      o[dn] = mfma16(pf1, vf1, o[dn]);
    }
  }
  float linv[4];
  #pragma unroll
  for (int r=0; r<4; ++r){
    float s = lsum[r];
    #pragma unroll
    for (int off=1; off<16; off<<=1) s += __shfl_xor(s, off, 64);
    linv[r] = 1.f / s;
  }
  #pragma unroll
  for (int dn=0; dn<4; ++dn){
    #pragma unroll
    for (int r=0; r<4; ++r){
      long oi = ((long)(b*LL + q0 + w*16 + qd*4 + r))*DD + h*64 + dn*16 + l15;
      ctx[oi] = f2bf(o[dn][r] * linv[r]);
    }
  }
}

extern "C" void kernel_launch(void* const* d_in, const int* in_sizes, int n_in,
                              void* d_out, int out_size, void* d_ws, size_t ws_size,
                              hipStream_t stream){
  char* ws = (char*)d_ws;
  size_t o = 0;
  auto alloc = [&](size_t b){ size_t r = o; o += (b + 255) & ~(size_t)255; return r; };
  int*   flags = (int*)(ws + alloc(256));
  size_t biasOff = alloc(8UL<<20);
  size_t qkvOff  = alloc(12UL<<20);
  UST* biasC = (UST*)(ws + biasOff);
  UST* qkv   = (UST*)(ws + qkvOff);
  UST* hb    = (UST*)(ws + biasOff);        // aliases biasC+qkv (dead by ffn1)
  UST* vT    = (UST*)(ws + alloc(4UL<<20));
  UST* xbf   = (UST*)(ws + alloc(2UL<<20));
  UST* wfuse = (UST*)(ws + alloc(131072*2));
  UST* bfuse = (UST*)(ws + alloc(1024));
  UST* ipw   = (UST*)(ws + alloc(786432*2));
  UST* ipb   = (UST*)(ws + alloc(3072*2));
  UST* outw  = (UST*)(ws + alloc(262144*2));
  UST* outb  = (UST*)(ws + alloc(1024));
  UST* w1    = (UST*)(ws + alloc(1048576*2));
  UST* b1    = (UST*)(ws + alloc(4096*2));
  UST* w2    = (UST*)(ws + alloc(1048576*2));
  UST* b2    = (UST*)(ws + alloc(1024));
  float* xf  = (float*)(ws + alloc((size_t)NT*DD*4));
  UST* xn    = (UST*)(ws + alloc((size_t)NT*DD*2));
  UST* ctx   = (UST*)(ws + alloc((size_t)NT*DD*2));
  float* x2  = (float*)(ws + alloc((size_t)NT*DD*4));

  detect_k<<<1, 64, 0, stream>>>(flags, (const UST*)d_in[0], (const unsigned int*)d_in[1]);

  CvtArgs ca;
  const int srcIdx[11] = {0,3,4,5,6,7,8,13,14,15,16};
  UST* dsts[11] = {xbf,wfuse,bfuse,ipw,ipb,outw,outb,w1,b1,w2,b2};
  const int ns[11] = {NT*IND, DD*IND, DD, 3*DD*DD, 3*DD, DD*DD, DD, FFD*DD, FFD, DD*FFD, DD};
  for (int i=0;i<11;i++){ ca.src[i]=d_in[srcIdx[i]]; ca.dst[i]=dsts[i]; ca.n[i]=ns[i]; }
  cvt_k<<<dim3(512,11), 256, 0, stream>>>(flags, ca);

  bias_k<<<BB*LL, 256, 0, stream>>>(flags, d_in[1], d_in[2], d_in[17], biasC);

  gemm2_k<2,0,0,1><<<dim3(32,8), 256, 0, stream>>>(flags, xbf, wfuse, bfuse, nullptr, xf, NT, DD, IND);
  ln_k<<<NT, 256, 0, stream>>>(flags, xf, d_in[9], d_in[10], xn);
  gemm2_k<4,0,0,0><<<dim3(32,12), 256, 0, stream>>>(flags, xn, ipw, ipb, nullptr, qkv, NT, 3*DD, DD);
  repack_v<<<512, 256, 0, stream>>>(qkv, vT);
  attn_k<<<512, 256, 0, stream>>>(qkv, vT, biasC, ctx);
  gemm2_k<2,0,1,1><<<dim3(32,8), 256, 0, stream>>>(flags, ctx, outw, outb, xf, x2, NT, DD, DD);
  ln_k<<<NT, 256, 0, stream>>>(flags, x2, d_in[11], d_in[12], xn);
  gemm2_k<4,1,0,0><<<dim3(32,16), 256, 0, stream>>>(flags, xn, w1, b1, nullptr, hb, NT, FFD, DD);
  gemm2_k<2,0,1,2><<<dim3(32,8), 256, 0, stream>>>(flags, hb, w2, b2, x2, d_out, NT, DD, FFD);
}